// Round 7
// baseline (173.012 us; speedup 1.0000x reference)
//
#include <hip/hip_runtime.h>
#include <hip/hip_bf16.h>

typedef short short8 __attribute__((ext_vector_type(8)));
typedef float float4v __attribute__((ext_vector_type(4)));

// ws layout: [0, 32KB) = We2 in bf16 MFMA-B-fragment order (16384 shorts)
//            float* F = (float*)ws + 8192, offsets below (in floats)
#define WS_T   0        // T[21][128]
#define WS_D   2688     // be2+bl2+br2+cr0
#define WS_C   2816     // cl0
#define WS_O   2944     // bl2+bo2
#define WS_A2  3072     // a2
#define WS_KEY 3200     // decoding-order keys[4096]

__device__ __forceinline__ unsigned int pack2bf(float a, float b) {
  // two fp32 -> packed bf16 pair (round-half-up; differs from RNE only on ties)
  union { float f; unsigned int u; } xa, xb;
  xa.f = a; xb.f = b;
  return ((xa.u + 0x8000u) >> 16) | ((xb.u + 0x8000u) & 0xFFFF0000u);
}

// ---------------------------------------------------------------------------
// Prologue (grid 38 x 256): block 0 = We2 swizzle (bf16, B-frag order) +
// collapsed constants; blocks 1..21 = T[v] = W_s[v] @ Wl2[128:,:];
// blocks 22..37 = decoding-order keys.
// ---------------------------------------------------------------------------
__global__ __launch_bounds__(256) void pg7_pre(
    const float* __restrict__ Wl2, const float* __restrict__ Wr2,
    const float* __restrict__ We2, const float* __restrict__ bl1,
    const float* __restrict__ bl2, const float* __restrict__ br2,
    const float* __restrict__ be2, const float* __restrict__ a2,
    const float* __restrict__ bo1, const float* __restrict__ bo2,
    const float* __restrict__ W_s, const float* __restrict__ mask,
    const float* __restrict__ chain_M, const float* __restrict__ z,
    void* __restrict__ ws)
{
  short* wsW = (short*)ws;
  float* F = (float*)ws + 8192;
  const int b = blockIdx.x, tid = threadIdx.x;
  if (b == 0) {
    for (int s = tid; s < 16384; s += 256) {
      const int row = s >> 7, c = s & 127;            // row = K idx, c = N idx
      const int q = row >> 5, lh = (row & 31) >> 3, j = row & 7;
      const int t = c >> 4, cl = c & 15;
      union { float f; unsigned int u; } x; x.f = We2[s];
      const unsigned int r = x.u + 0x7FFFu + ((x.u >> 16) & 1u);  // RNE
      wsW[(((q * 8 + t) * 64) + lh * 16 + cl) * 8 + j] = (short)(r >> 16);
    }
    if (tid < 128) {
      const int c = tid;
      float cl0 = 0.f, cr0 = 0.f;
      for (int i = 0; i < 128; i++) {
        const float s = bl1[i] + bo1[i];     // layer-1 output (constant vector)
        cl0 += s * Wl2[i * 128 + c];
        cr0 += s * Wr2[i * 128 + c];
      }
      F[WS_D + c]  = be2[c] + bl2[c] + br2[c] + cr0;
      F[WS_C + c]  = cl0;
      F[WS_O + c]  = bl2[c] + bo2[c];
      F[WS_A2 + c] = a2[c];
    }
  } else if (b <= 21) {
    const int v = b - 1;
    if (tid < 128) {
      const int c = tid;
      float acc = 0.f;
      for (int h = 0; h < 128; h++)
        acc += W_s[v * 128 + h] * Wl2[(128 + h) * 128 + c];
      F[WS_T + v * 128 + c] = acc;
    }
  } else {
    const int n = (b - 22) * 256 + tid;
    F[WS_KEY + n] = (chain_M[n] * mask[n] + 1e-4f) * fabsf(z[n]);
  }
}

// ---------------------------------------------------------------------------
// Main (grid 1024 x 256): one wave per node, ZERO block-wide barriers.
// B-fragments + T + constants stream from L2-hot ws; LDS is wave-private
// scratch only (edge meta broadcast + 128-float transpose for logits).
// B tiles depend on (q,t) only -> loaded once, feed both edge groups.
// ---------------------------------------------------------------------------
__global__ __launch_bounds__(256) void pg7_main(
    const float* __restrict__ E, const int* __restrict__ E_idx,
    const int* __restrict__ S, const float* __restrict__ mask,
    const float* __restrict__ W_out, const float* __restrict__ b_out,
    const void* __restrict__ ws, float* __restrict__ out)
{
  __shared__ float ldsout[4][128];   // wave-private transpose buffer
  __shared__ float ldswk[4][32];     // wave-private edge meta
  __shared__ int   ldsrv[4][32];

  const short* wsW = (const short*)ws;
  const float* F = (const float*)ws + 8192;
  const int tid  = threadIdx.x;
  const int wave = tid >> 6;
  const int lane = tid & 63;
  const int quad = lane >> 4;
  const int lid  = lane & 15;
  const int n    = blockIdx.x * 4 + wave;
  const float maskn = mask[n];

  // --- edge meta (wave-private LDS broadcast; DS is in-order per wave)
  if (lane < 32) {
    const int j = E_idx[n * 32 + lane];
    const float keyn = F[WS_KEY + n], kj = F[WS_KEY + j];
    // stable argsort: j ordered before n  <=>  (key[j], j) <lex (key[n], n)
    const int before = (kj < keyn) || (kj == keyn && j < n);
    ldswk[wave][lane] = before ? maskn : 0.f;
    ldsrv[wave][lane] = S[j] * 128;
  }
  __builtin_amdgcn_wave_barrier();

  // --- A fragments: A[m=lid][k = q*32 + quad*8 + j]
  short8 afr[2][4];
#pragma unroll
  for (int g = 0; g < 2; g++) {
    const float* erow = E + (size_t)(n * 32 + g * 16 + lid) * 128 + quad * 8;
#pragma unroll
    for (int q = 0; q < 4; q++) {
      const float4 A = *(const float4*)(erow + q * 32);
      const float4 B = *(const float4*)(erow + q * 32 + 4);
      union { short8 s; unsigned int u[4]; } v;
      v.u[0] = pack2bf(A.x, A.y);
      v.u[1] = pack2bf(A.z, A.w);
      v.u[2] = pack2bf(B.x, B.y);
      v.u[3] = pack2bf(B.z, B.w);
      afr[g][q] = v.s;
    }
  }

  int rows[2][4]; float wks[2][4];
#pragma unroll
  for (int g = 0; g < 2; g++)
#pragma unroll
    for (int r = 0; r < 4; r++) {
      const int kk = g * 16 + quad * 4 + r;
      rows[g][r] = ldsrv[wave][kk];
      wks[g][r]  = ldswk[wave][kk];
    }

  // --- K-loop: load each B tile once, feed both edge groups
  float part[2][4] = {{0.f, 0.f, 0.f, 0.f}, {0.f, 0.f, 0.f, 0.f}};
#pragma unroll
  for (int t = 0; t < 8; t++) {
    short8 bfr[4];
#pragma unroll
    for (int q = 0; q < 4; q++)
      bfr[q] = *(const short8*)(wsW + (((q * 8 + t) * 64) + lane) * 8);
    float4v ac0 = {0.f, 0.f, 0.f, 0.f}, ac1 = {0.f, 0.f, 0.f, 0.f};
#pragma unroll
    for (int q = 0; q < 4; q++) {
      ac0 = __builtin_amdgcn_mfma_f32_16x16x32_bf16(afr[0][q], bfr[q], ac0, 0, 0, 0);
      ac1 = __builtin_amdgcn_mfma_f32_16x16x32_bf16(afr[1][q], bfr[q], ac1, 0, 0, 0);
    }
    const int c = t * 16 + lid;
    const float dvt  = F[WS_D + c] + maskn * F[WS_C + c];
    const float a2vt = F[WS_A2 + c];
#pragma unroll
    for (int r = 0; r < 4; r++) {
      float v0 = ac0[r] + dvt + wks[0][r] * F[WS_T + rows[0][r] + c];
      float v1 = ac1[r] + dvt + wks[1][r] * F[WS_T + rows[1][r] + c];
      v0 = fmaxf(v0, 0.f) + 0.2f * fminf(v0, 0.f);   // leaky_relu(0.2)
      v1 = fmaxf(v1, 0.f) + 0.2f * fminf(v1, 0.f);
      part[0][r] = fmaf(v0, a2vt, part[0][r]);
      part[1][r] = fmaf(v1, a2vt, part[1][r]);
    }
  }
  // reduce scores over the 16 c-lanes of each quad
  float sreg[2][4];
#pragma unroll
  for (int g = 0; g < 2; g++)
#pragma unroll
    for (int r = 0; r < 4; r++) {
      float v = part[g][r];
      v += __shfl_xor(v, 1);
      v += __shfl_xor(v, 2);
      v += __shfl_xor(v, 4);
      v += __shfl_xor(v, 8);
      sreg[g][r] = v;   // score for edge kk = g*16 + quad*4 + r (uniform in quad)
    }

  // --- softmax over 32 neighbor scores
  float mx = -1e30f;
#pragma unroll
  for (int g = 0; g < 2; g++)
#pragma unroll
    for (int r = 0; r < 4; r++) mx = fmaxf(mx, sreg[g][r]);
  mx = fmaxf(mx, __shfl_xor(mx, 16));
  mx = fmaxf(mx, __shfl_xor(mx, 32));
  float eg[2][4], esum = 0.f;
#pragma unroll
  for (int g = 0; g < 2; g++)
#pragma unroll
    for (int r = 0; r < 4; r++) {
      eg[g][r] = expf(sreg[g][r] - mx);
      esum += eg[g][r];
    }
  esum += __shfl_xor(esum, 16);
  esum += __shfl_xor(esum, 32);
  const float inv = 1.f / esum;
  float cg[2][4];
#pragma unroll
  for (int g = 0; g < 2; g++)
#pragma unroll
    for (int r = 0; r < 4; r++) cg[g][r] = eg[g][r] * inv * wks[g][r];

  // --- aggregation: out_vec[c] = O + maskn*cl0 + sum_k coef_k * T[S_jk][c]
  float o0 = F[WS_O + lane]      + maskn * F[WS_C + lane];
  float o1 = F[WS_O + lane + 64] + maskn * F[WS_C + lane + 64];
#pragma unroll
  for (int kk = 0; kk < 32; kk++) {
    const int g = kk >> 4, sq = (kk >> 2) & 3, r = kk & 3;
    const float cf = __shfl(cg[g][r], sq * 16);   // broadcast from source quad
    const int row = ldsrv[wave][kk];              // same-addr LDS read: broadcast
    o0 = fmaf(cf, F[WS_T + row + lane], o0);
    o1 = fmaf(cf, F[WS_T + row + lane + 64], o1);
  }
  ldsout[wave][lane]      = o0;
  ldsout[wave][lane + 64] = o1;
  __builtin_amdgcn_wave_barrier();

  // --- logits (lanes 0..20) + log_softmax over V=21
  float l0 = 0.f, l1 = 0.f, l2 = 0.f, l3 = 0.f;
  if (lane < 21) {
    const float* wo = W_out + lane;
#pragma unroll 8
    for (int c = 0; c < 128; c += 4) {
      l0 = fmaf(ldsout[wave][c],     wo[c * 21],       l0);
      l1 = fmaf(ldsout[wave][c + 1], wo[(c + 1) * 21], l1);
      l2 = fmaf(ldsout[wave][c + 2], wo[(c + 2) * 21], l2);
      l3 = fmaf(ldsout[wave][c + 3], wo[(c + 3) * 21], l3);
    }
  }
  float lg = (lane < 21) ? (b_out[lane] + ((l0 + l1) + (l2 + l3))) : -1e30f;
  float lmx = lg;
  lmx = fmaxf(lmx, __shfl_xor(lmx, 1));
  lmx = fmaxf(lmx, __shfl_xor(lmx, 2));
  lmx = fmaxf(lmx, __shfl_xor(lmx, 4));
  lmx = fmaxf(lmx, __shfl_xor(lmx, 8));
  lmx = fmaxf(lmx, __shfl_xor(lmx, 16));
  float ex = (lane < 21) ? expf(lg - lmx) : 0.f;
  float es = ex;
  es += __shfl_xor(es, 1);
  es += __shfl_xor(es, 2);
  es += __shfl_xor(es, 4);
  es += __shfl_xor(es, 8);
  es += __shfl_xor(es, 16);
  if (lane < 21)
    out[n * 21 + lane] = lg - lmx - logf(es);
}

extern "C" void kernel_launch(void* const* d_in, const int* in_sizes, int n_in,
                              void* d_out, int out_size, void* d_ws, size_t ws_size,
                              hipStream_t stream)
{
  const float* E       = (const float*)d_in[0];
  const int*   E_idx   = (const int*)d_in[1];
  const int*   S       = (const int*)d_in[2];
  const float* mask    = (const float*)d_in[3];
  const float* chain_M = (const float*)d_in[4];
  const float* z       = (const float*)d_in[5];
  const float* bl1     = (const float*)d_in[7];
  const float* bo1     = (const float*)d_in[13];
  const float* Wl2     = (const float*)d_in[14];
  const float* bl2     = (const float*)d_in[15];
  const float* Wr2     = (const float*)d_in[16];
  const float* br2     = (const float*)d_in[17];
  const float* We2     = (const float*)d_in[18];
  const float* be2     = (const float*)d_in[19];
  const float* a2      = (const float*)d_in[20];
  const float* bo2     = (const float*)d_in[21];
  const float* W_s     = (const float*)d_in[22];
  const float* W_out   = (const float*)d_in[23];
  const float* b_out   = (const float*)d_in[24];

  pg7_pre<<<38, 256, 0, stream>>>(Wl2, Wr2, We2, bl1, bl2, br2, be2, a2,
                                  bo1, bo2, W_s, mask, chain_M, z, d_ws);
  pg7_main<<<1024, 256, 0, stream>>>(E, E_idx, S, mask, W_out, b_out, d_ws,
                                     (float*)d_out);
}